// Round 7
// baseline (349.552 us; speedup 1.0000x reference)
//
#include <hip/hip_runtime.h>
#include <hip/hip_bf16.h>

typedef __attribute__((ext_vector_type(8))) short bf16x8;
typedef __attribute__((ext_vector_type(4))) float f32x4;

#define T_TOK 1370
#define DDIM  768
#define SCV   1369   // valid tokens per slab
#define SCP   1408   // s slab padded rows
#define MQP   1536   // q padded rows (3*512)
#define NB    8
#define NSLAB 32
#define NST   44     // s tiles of 128 per batch (4 slabs * 11)

#define MEMFENCE asm volatile("" ::: "memory")
#define BARRIER  do { __builtin_amdgcn_s_barrier(); MEMFENCE; } while (0)
#define VMCNT0   asm volatile("s_waitcnt vmcnt(0)" ::: "memory")
#define VMCNT5   asm volatile("s_waitcnt vmcnt(5)" ::: "memory")
#define LGKMCNT0 asm volatile("s_waitcnt lgkmcnt(0)" ::: "memory")

__device__ __forceinline__ unsigned short f2bf(float x) {
  union { __hip_bfloat16 h; unsigned short u; } cv;
  cv.h = __float2bfloat16(x);
  return cv.u;
}

#define GLOAD_LDS16(g, l)                                                     \
  __builtin_amdgcn_global_load_lds(                                           \
      (const __attribute__((address_space(1))) unsigned int*)(g),             \
      (__attribute__((address_space(3))) unsigned int*)(l), 16, 0, 0)

// One block per output row: mean over 3 layers -> l2norm -> bf16 store.
// dst layout: [8][1536][768] bf16, rows >= 1369 zeroed.
extern "C" __global__ __launch_bounds__(192) void prep_q_kernel(
    const float* __restrict__ src, unsigned short* __restrict__ dst,
    size_t lstride)
{
  const int row  = blockIdx.x;   // 0..1535
  const int slab = blockIdx.y;   // 0..7
  const int t    = threadIdx.x;  // 0..191
  unsigned short* drow = dst + ((size_t)slab * MQP + row) * DDIM;
  if (row >= SCV) {
    ushort4 z; z.x = z.y = z.z = z.w = 0;
    reinterpret_cast<ushort4*>(drow)[t] = z;
    return;
  }
  const float* base = src + ((size_t)slab * T_TOK + row + 1) * DDIM;
  float4 a = reinterpret_cast<const float4*>(base)[t];
  float4 b = reinterpret_cast<const float4*>(base + lstride)[t];
  float4 c = reinterpret_cast<const float4*>(base + 2 * lstride)[t];
  const float k3 = 1.0f / 3.0f;
  float4 m;
  m.x = (a.x + b.x + c.x) * k3;
  m.y = (a.y + b.y + c.y) * k3;
  m.z = (a.z + b.z + c.z) * k3;
  m.w = (a.w + b.w + c.w) * k3;
  float ss = m.x * m.x + m.y * m.y + m.z * m.z + m.w * m.w;
  #pragma unroll
  for (int d = 1; d < 64; d <<= 1) ss += __shfl_xor(ss, d);
  __shared__ float wsum[3];
  if ((t & 63) == 0) wsum[t >> 6] = ss;
  __syncthreads();
  float tot = wsum[0] + wsum[1] + wsum[2];
  float rn = 1.0f / fmaxf(sqrtf(tot), 1e-12f);
  ushort4 o;
  o.x = f2bf(m.x * rn); o.y = f2bf(m.y * rn);
  o.z = f2bf(m.z * rn); o.w = f2bf(m.w * rn);
  reinterpret_cast<ushort4*>(drow)[t] = o;
}

// Fused: prep own 128-row s-tile (f32 -> mean -> l2norm -> bf16 in ws),
// then GEMM-with-max vs all of xq[n]: 3 A-chunks of 512 x 24 K-steps(32),
// ring-3 LDS, counted vmcnt(5), 8 waves (4M x 2N, per-wave 128x64).
// Grid: 352 blocks (flat = st*8 + n style: n = flat&7 -> one batch per XCD).
// part: [8][44][1536] float.
extern "C" __global__ __launch_bounds__(512, 2) void fused_kernel(
    const float* __restrict__ s_feats,
    const unsigned short* __restrict__ xq,
    unsigned short* __restrict__ xst,
    float* __restrict__ part)
{
  const int flat = blockIdx.x;   // 0..351
  const int n    = flat & 7;     // XCD k owns batch k (round-robin dispatch)
  const int st   = flat >> 3;    // 0..43
  const int slab = st / 11;
  const int lt   = st - slab * 11;

  const int tid  = threadIdx.x;  // 0..511
  const int lane = tid & 63;
  const int w    = tid >> 6;     // 0..7
  const int wr   = w >> 1;       // 0..3 : 128-row A band of 512
  const int wc   = w & 1;        // 0..1 : 64-col B half of 128
  const int l15  = lane & 15, l4 = lane >> 4;

  // ring: [3] x (A 512x32 | B 128x32) bf16 = 3 x 40 KB = 120 KB
  __shared__ unsigned short ring[3][20480];
  __shared__ float sfold[1024];

  unsigned short* bws = xst + (size_t)flat * (128 * DDIM);

  // ---------------- phase 1: prep this block's 128 s-rows ----------------
  {
    const float* srow0 =
        s_feats + ((size_t)(n * 4 + slab) * T_TOK + 1 + (size_t)lt * 128) * DDIM;
    const size_t lstr = (size_t)NSLAB * T_TOK * DDIM;
    const float k3 = 1.0f / 3.0f;
    for (int i2 = 0; i2 < 16; i2 += 2) {
      #pragma unroll
      for (int u = 0; u < 2; ++u) {
        const int rr = w * 16 + i2 + u;           // 0..127 (wave-uniform)
        unsigned short* dr = bws + (size_t)rr * DDIM;
        if (lt * 128 + rr < SCV) {
          const float* rb = srow0 + (size_t)rr * DDIM;
          float4 m[3];
          float ss = 0.f;
          #pragma unroll
          for (int c = 0; c < 3; ++c) {
            const int e = (lane + c * 64) * 4;
            float4 a = *reinterpret_cast<const float4*>(rb + e);
            float4 b = *reinterpret_cast<const float4*>(rb + lstr + e);
            float4 d = *reinterpret_cast<const float4*>(rb + 2 * lstr + e);
            m[c].x = (a.x + b.x + d.x) * k3;
            m[c].y = (a.y + b.y + d.y) * k3;
            m[c].z = (a.z + b.z + d.z) * k3;
            m[c].w = (a.w + b.w + d.w) * k3;
            ss += m[c].x * m[c].x + m[c].y * m[c].y +
                  m[c].z * m[c].z + m[c].w * m[c].w;
          }
          #pragma unroll
          for (int d = 1; d < 64; d <<= 1) ss += __shfl_xor(ss, d);
          const float rn = 1.0f / fmaxf(sqrtf(ss), 1e-12f);
          #pragma unroll
          for (int c = 0; c < 3; ++c) {
            ushort4 o;
            o.x = f2bf(m[c].x * rn); o.y = f2bf(m[c].y * rn);
            o.z = f2bf(m[c].z * rn); o.w = f2bf(m[c].w * rn);
            *reinterpret_cast<ushort4*>(dr + (lane + c * 64) * 4) = o;
          }
        } else {
          ushort4 z; z.x = z.y = z.z = z.w = 0;
          #pragma unroll
          for (int c = 0; c < 3; ++c)
            *reinterpret_cast<ushort4*>(dr + (lane + c * 64) * 4) = z;
        }
      }
    }
  }
  VMCNT0;
  __syncthreads();   // B tile visible (same CU) to global_load_lds below

  // ---------------- phase 2: GEMM with running max ----------------
  const unsigned short* gAn = xq + (size_t)n * MQP * DDIM;

  // staging offsets. A: 32 chunks of 1 KB (16 rows x 64 B), wave owns w*4..+3;
  // B: 8 chunks, wave owns chunk w. lane -> row c*16+(lane>>2), 16-B slot
  // lane&3, source pre-swizzled by slot^(row&3); LDS dest linear.
  int aoffg[4], aldso[4], boffg0, bldso0;
  #pragma unroll
  for (int i = 0; i < 4; ++i) {
    int c = w * 4 + i;
    int r = c * 16 + (lane >> 2);
    aoffg[i] = r * DDIM + (((lane & 3) ^ (r & 3)) << 3);
    aldso[i] = c * 512;
  }
  {
    int r = w * 16 + (lane >> 2);
    boffg0 = r * DDIM + (((lane & 3) ^ (r & 3)) << 3);
    bldso0 = 16384 + w * 512;
  }

  // fragment read byte offsets (same involution)
  const int kxor = (l4 * 16) ^ ((l15 & 3) << 4);
  int aoff[8], boff[4];
  #pragma unroll
  for (int mf = 0; mf < 8; ++mf)
    aoff[mf] = (wr * 128 + mf * 16 + l15) * 64 + kxor;
  #pragma unroll
  for (int nf = 0; nf < 4; ++nf)
    boff[nf] = 32768 + (wc * 64 + nf * 16 + l15) * 64 + kxor;

  bool colv[4];
  #pragma unroll
  for (int nf = 0; nf < 4; ++nf)
    colv[nf] = (lt * 128 + wc * 64 + nf * 16 + l15) < SCV;

  f32x4 acc[8][4];
  const f32x4 zz = {0.f, 0.f, 0.f, 0.f};
  #pragma unroll
  for (int a = 0; a < 8; ++a)
    #pragma unroll
    for (int b = 0; b < 4; ++b) acc[a][b] = zz;

  #define ISSUE(S)                                                            \
    do {                                                                      \
      int s_ = (S);                                                           \
      int ck_ = s_ / 24, kk_ = s_ - ck_ * 24;                                 \
      const unsigned short* ga_ = gAn + (size_t)(ck_ * 512) * DDIM + kk_ * 32;\
      const unsigned short* gb_ = bws + kk_ * 32;                             \
      unsigned short* lb_ = ring[s_ % 3];                                     \
      _Pragma("unroll") for (int i = 0; i < 4; ++i)                           \
        GLOAD_LDS16(ga_ + aoffg[i], lb_ + aldso[i]);                          \
      GLOAD_LDS16(gb_ + boffg0, lb_ + bldso0);                                \
    } while (0)

  ISSUE(0);
  ISSUE(1);
  VMCNT5;   // step-0 buffer landed; step-1's 5 still flying
  BARRIER;

  for (int step = 0; step < 72; ++step) {
    if (step + 2 < 72) ISSUE(step + 2);

    const char* Cb = reinterpret_cast<const char*>(ring[step % 3]);
    bf16x8 bfr[4], af[8];
    #pragma unroll
    for (int nf = 0; nf < 4; ++nf)
      bfr[nf] = *reinterpret_cast<const bf16x8*>(Cb + boff[nf]);
    #pragma unroll
    for (int mf = 0; mf < 8; ++mf)
      af[mf] = *reinterpret_cast<const bf16x8*>(Cb + aoff[mf]);

    __builtin_amdgcn_s_setprio(1);
    #pragma unroll
    for (int mf = 0; mf < 8; ++mf)
      #pragma unroll
      for (int nf = 0; nf < 4; ++nf)
        acc[mf][nf] = __builtin_amdgcn_mfma_f32_16x16x32_bf16(
            af[mf], bfr[nf], acc[mf][nf], 0, 0, 0);
    __builtin_amdgcn_s_setprio(0);

    if ((step % 24) == 23) {
      // fold chunk: mask invalid cols, butterfly over 16 col-lanes,
      // cross-wave combine, write 512-row partial; reset acc.
      const int ck = step / 24;
      float rm[8][4];
      #pragma unroll
      for (int mf = 0; mf < 8; ++mf)
        #pragma unroll
        for (int j = 0; j < 4; ++j) {
          float v = -1e30f;
          #pragma unroll
          for (int nf = 0; nf < 4; ++nf)
            if (colv[nf]) v = fmaxf(v, acc[mf][nf][j]);
          rm[mf][j] = v;
        }
      #pragma unroll
      for (int msk = 1; msk < 16; msk <<= 1)
        #pragma unroll
        for (int mf = 0; mf < 8; ++mf)
          #pragma unroll
          for (int j = 0; j < 4; ++j)
            rm[mf][j] = fmaxf(rm[mf][j], __shfl_xor(rm[mf][j], msk));
      if (l15 == 0) {
        #pragma unroll
        for (int mf = 0; mf < 8; ++mf)
          #pragma unroll
          for (int j = 0; j < 4; ++j)
            sfold[wc * 512 + wr * 128 + mf * 16 + l4 * 4 + j] = rm[mf][j];
      }
      LGKMCNT0;
      BARRIER;
      {
        float v = fmaxf(sfold[tid], sfold[512 + tid]);
        part[((size_t)(n * NST + st)) * MQP + ck * 512 + tid] = v;
      }
      #pragma unroll
      for (int a = 0; a < 8; ++a)
        #pragma unroll
        for (int b = 0; b < 4; ++b) acc[a][b] = zz;
    }

    if (step < 70)       VMCNT5;
    else if (step == 70) VMCNT0;
    if (step < 71) BARRIER;
  }
  #undef ISSUE
}

extern "C" __global__ void finalize_kernel(const float* __restrict__ part,
                                           float* __restrict__ out) {
  int i = blockIdx.x * 256 + threadIdx.x;
  if (i >= NB * SCV) return;
  int n = i / SCV, q = i - n * SCV;
  const float* p = part + (size_t)n * NST * MQP + q;
  float m = p[0];
  #pragma unroll 4
  for (int g = 1; g < NST; ++g) m = fmaxf(m, p[(size_t)g * MQP]);
  out[i] = 1.0f - m;
}

extern "C" void kernel_launch(void* const* d_in, const int* in_sizes, int n_in,
                              void* d_out, int out_size, void* d_ws, size_t ws_size,
                              hipStream_t stream) {
  const float* q_feats = (const float*)d_in[0];  // (3, 8, 1370, 768) f32
  const float* s_feats = (const float*)d_in[1];  // (3, 32, 1370, 768) f32
  float* out = (float*)d_out;                    // (8, 1, 37, 37) f32

  char* ws = (char*)d_ws;
  const size_t xq_bytes  = (size_t)NB * MQP * DDIM * 2;          // 18,874,368
  const size_t xst_bytes = (size_t)NB * NST * 128 * DDIM * 2;    // 69,206,016
  unsigned short* xq  = (unsigned short*)ws;
  unsigned short* xst = (unsigned short*)(ws + xq_bytes);
  float* part = (float*)(ws + xq_bytes + xst_bytes);             // 8*44*1536 f32

  prep_q_kernel<<<dim3(MQP, NB), 192, 0, stream>>>(
      q_feats, xq, (size_t)NB * T_TOK * DDIM);
  fused_kernel<<<dim3(NB * NST), 512, 0, stream>>>(s_feats, xq, xst, part);
  finalize_kernel<<<dim3((NB * SCV + 255) / 256), 256, 0, stream>>>(part, out);
}

// Round 8
// 236.928 us; speedup vs baseline: 1.4754x; 1.4754x over previous
//
#include <hip/hip_runtime.h>
#include <hip/hip_bf16.h>

typedef __attribute__((ext_vector_type(8))) short bf16x8;
typedef __attribute__((ext_vector_type(4))) float f32x4;

#define T_TOK 1370
#define DDIM  768
#define SCV   1369   // valid tokens per slab
#define SCP   1408   // s slab padded rows (11*128)
#define MQP   1536   // q padded rows (6*256)
#define NB    8
#define NSLAB 32
#define NST   44     // s tiles of 128 (4 slabs * 11)
#define NMT   6      // m tiles of 256

#define MEMFENCE asm volatile("" ::: "memory")
#define BARRIER  do { __builtin_amdgcn_s_barrier(); MEMFENCE; } while (0)

__device__ __forceinline__ unsigned short f2bf(float x) {
  union { __hip_bfloat16 h; unsigned short u; } cv;
  cv.h = __float2bfloat16(x);
  return cv.u;
}

#define GLOAD_LDS16(g, l)                                                     \
  __builtin_amdgcn_global_load_lds(                                           \
      (const __attribute__((address_space(1))) unsigned int*)(g),             \
      (__attribute__((address_space(3))) unsigned int*)(l), 16, 0, 0)

// One block per output row: mean over 3 layers -> l2norm -> bf16 store.
// dst layout: [slabs][pad][768] bf16, rows >= 1369 zeroed. pad via gridDim.x.
extern "C" __global__ __launch_bounds__(192) void prep_kernel(
    const float* __restrict__ src, unsigned short* __restrict__ dst,
    size_t lstride)
{
  const int row  = blockIdx.x;
  const int slab = blockIdx.y;
  const int t    = threadIdx.x;  // 0..191, each owns one float4 (768 = 192*4)
  unsigned short* drow = dst + ((size_t)slab * gridDim.x + row) * DDIM;
  if (row >= SCV) {
    ushort4 z; z.x = z.y = z.z = z.w = 0;
    reinterpret_cast<ushort4*>(drow)[t] = z;
    return;
  }
  const float* base = src + ((size_t)slab * T_TOK + row + 1) * DDIM;
  float4 a = reinterpret_cast<const float4*>(base)[t];
  float4 b = reinterpret_cast<const float4*>(base + lstride)[t];
  float4 c = reinterpret_cast<const float4*>(base + 2 * lstride)[t];
  const float k3 = 1.0f / 3.0f;
  float4 m;
  m.x = (a.x + b.x + c.x) * k3;
  m.y = (a.y + b.y + c.y) * k3;
  m.z = (a.z + b.z + c.z) * k3;
  m.w = (a.w + b.w + c.w) * k3;
  float ss = m.x * m.x + m.y * m.y + m.z * m.z + m.w * m.w;
  #pragma unroll
  for (int d = 1; d < 64; d <<= 1) ss += __shfl_xor(ss, d);
  __shared__ float wsum[3];
  if ((t & 63) == 0) wsum[t >> 6] = ss;
  __syncthreads();
  float tot = wsum[0] + wsum[1] + wsum[2];
  float rn = 1.0f / fmaxf(sqrtf(tot), 1e-12f);
  ushort4 o;
  o.x = f2bf(m.x * rn); o.y = f2bf(m.y * rn);
  o.z = f2bf(m.z * rn); o.w = f2bf(m.w * rn);
  reinterpret_cast<ushort4*>(drow)[t] = o;
}

// 256x128 tile, BK=32, 4 waves (2Mx2N, per-wave 128x64), ring-3 LDS,
// counted vmcnt(6), 2 blocks/CU. Conflict-free swizzle: slot ^= (row>>1)&3
// spreads 8 consecutive rows across all 8 bank-quads. part: [8][44][1536].
extern "C" __global__ __launch_bounds__(256, 2) void simmax_kernel(
    const unsigned short* __restrict__ xq,
    const unsigned short* __restrict__ xs,
    float* __restrict__ part)
{
  // XCD-chunked bijective remap: nwg = 2112 = 8*264; XCD k owns batch n=k,
  // mt varies fastest so 6 consecutive blocks share one B s-tile.
  const int flat = blockIdx.x + NMT * (blockIdx.y + NST * blockIdx.z);
  const int swz  = (flat & 7) * (NMT * NST) + (flat >> 3);
  const int mt   = swz % NMT;
  const int st   = (swz / NMT) % NST;
  const int n    = swz / (NMT * NST);

  const int tid = threadIdx.x;
  const int lane = tid & 63;
  const int w    = tid >> 6;    // 0..3
  const int wr = w >> 1;        // 0..1 (128-row band of 256)
  const int wc = w & 1;         // 0..1 (64-col half of 128)
  const int l15 = lane & 15, l4 = lane >> 4;

  // ring: [3] x (A 256x32 | B 128x32) bf16 = 3 x 24 KB = 72 KB
  __shared__ unsigned short ring[3][12288];

  const int slab = st / 11;
  const int lt   = st - slab * 11;
  const unsigned short* gA = xq + ((size_t)n * MQP + (size_t)mt * 256) * DDIM;
  const unsigned short* gB =
      xs + ((size_t)(n * 4 + slab) * SCP + (size_t)lt * 128) * DDIM;

  // staging: 1-KB chunks = 16 rows x 64 B. A = 16 chunks (wave owns w*4..+3),
  // B = 8 chunks (wave owns w*2..+1). lane -> row c*16+(lane>>2), 16-B slot
  // (lane&3). Source pre-swizzled slot^((row>>1)&3); LDS dest linear; read
  // XORs the same involution => 8 consecutive rows hit 8 distinct bank-quads.
  int aoffg[4], aldso[4], boffg[2], bldso[2];
  #pragma unroll
  for (int i = 0; i < 4; ++i) {
    int c = w * 4 + i;
    int r = c * 16 + (lane >> 2);
    aoffg[i] = r * DDIM + (((lane & 3) ^ ((r >> 1) & 3)) << 3);
    aldso[i] = c * 512;
  }
  #pragma unroll
  for (int i = 0; i < 2; ++i) {
    int c = w * 2 + i;
    int r = c * 16 + (lane >> 2);
    boffg[i] = r * DDIM + (((lane & 3) ^ ((r >> 1) & 3)) << 3);
    bldso[i] = 8192 + c * 512;   // B region starts at 16 KB
  }

  // fragment read byte offsets: row*64 + ((l4*16) ^ (((row>>1)&3)<<4));
  // (row>>1)&3 == (l15>>1)&3 for every fragment row (16-aligned bases).
  const int kxor = (l4 * 16) ^ (((l15 >> 1) & 3) << 4);
  int aoff[8], boff[4];
  #pragma unroll
  for (int mf = 0; mf < 8; ++mf)
    aoff[mf] = (wr * 128 + mf * 16 + l15) * 64 + kxor;
  #pragma unroll
  for (int nf = 0; nf < 4; ++nf)
    boff[nf] = 16384 + (wc * 64 + nf * 16 + l15) * 64 + kxor;

  f32x4 acc[8][4];
  {
    f32x4 zz = {0.f, 0.f, 0.f, 0.f};
    #pragma unroll
    for (int a = 0; a < 8; ++a)
      #pragma unroll
      for (int b = 0; b < 4; ++b) acc[a][b] = zz;
  }

  #define ISSUE(KT, RB)                                                       \
    do {                                                                      \
      const unsigned short* ga_ = gA + (KT) * 32;                             \
      const unsigned short* gb_ = gB + (KT) * 32;                             \
      unsigned short* lb_ = ring[RB];                                         \
      _Pragma("unroll") for (int i = 0; i < 4; ++i)                           \
        GLOAD_LDS16(ga_ + aoffg[i], lb_ + aldso[i]);                          \
      _Pragma("unroll") for (int i = 0; i < 2; ++i)                           \
        GLOAD_LDS16(gb_ + boffg[i], lb_ + bldso[i]);                          \
    } while (0)

  // prologue: fill pipeline 2 deep
  ISSUE(0, 0);
  ISSUE(1, 1);
  asm volatile("s_waitcnt vmcnt(6)" ::: "memory");  // kt0 landed, kt1 flying
  BARRIER;

  for (int kt = 0; kt < 24; ++kt) {
    if (kt + 2 < 24) ISSUE(kt + 2, (kt + 2) % 3);

    const char* Cb = reinterpret_cast<const char*>(ring[kt % 3]);
    bf16x8 bfr[4], af[8];
    #pragma unroll
    for (int nf = 0; nf < 4; ++nf)
      bfr[nf] = *reinterpret_cast<const bf16x8*>(Cb + boff[nf]);
    #pragma unroll
    for (int mf = 0; mf < 8; ++mf)
      af[mf] = *reinterpret_cast<const bf16x8*>(Cb + aoff[mf]);

    __builtin_amdgcn_s_setprio(1);
    #pragma unroll
    for (int mf = 0; mf < 8; ++mf)
      #pragma unroll
      for (int nf = 0; nf < 4; ++nf)
        acc[mf][nf] = __builtin_amdgcn_mfma_f32_16x16x32_bf16(
            af[mf], bfr[nf], acc[mf][nf], 0, 0, 0);
    __builtin_amdgcn_s_setprio(0);

    // wait for NEXT buffer's batch (issued a full K-step ago); keep the
    // just-issued 6 in flight across the barrier.
    if (kt < 22)       asm volatile("s_waitcnt vmcnt(6)" ::: "memory");
    else if (kt == 22) asm volatile("s_waitcnt vmcnt(0)" ::: "memory");
    if (kt < 23) BARRIER;
  }

  // ---- epilogue: masked running max, butterfly, cross-wave combine
  float rmax[8][4];
  #pragma unroll
  for (int a = 0; a < 8; ++a)
    #pragma unroll
    for (int b = 0; b < 4; ++b) rmax[a][b] = -1e30f;

  #pragma unroll
  for (int nf = 0; nf < 4; ++nf) {
    int col = lt * 128 + wc * 64 + nf * 16 + l15;
    if (col < SCV) {
      #pragma unroll
      for (int mf = 0; mf < 8; ++mf)
        #pragma unroll
        for (int j = 0; j < 4; ++j)
          rmax[mf][j] = fmaxf(rmax[mf][j], acc[mf][nf][j]);
    }
  }

  #pragma unroll
  for (int msk = 1; msk < 16; msk <<= 1)
    #pragma unroll
    for (int mf = 0; mf < 8; ++mf)
      #pragma unroll
      for (int j = 0; j < 4; ++j)
        rmax[mf][j] = fmaxf(rmax[mf][j], __shfl_xor(rmax[mf][j], msk));

  __syncthreads();
  float* buf = reinterpret_cast<float*>(&ring[0][0]);  // 2 x 256 floats
  if (l15 == 0) {
    #pragma unroll
    for (int mf = 0; mf < 8; ++mf)
      #pragma unroll
      for (int j = 0; j < 4; ++j) {
        int r = wr * 128 + mf * 16 + l4 * 4 + j;   // 0..255
        buf[wc * 256 + r] = rmax[mf][j];
      }
  }
  __syncthreads();
  if (tid < 256) {
    float v = fmaxf(buf[tid], buf[256 + tid]);
    part[((size_t)n * NST + st) * MQP + (size_t)mt * 256 + tid] = v;
  }
}

extern "C" __global__ void finalize_kernel(const float* __restrict__ part,
                                           float* __restrict__ out) {
  int i = blockIdx.x * 256 + threadIdx.x;
  if (i >= NB * SCV) return;
  int n = i / SCV, q = i - n * SCV;
  const float* p = part + (size_t)n * NST * MQP + q;
  float m = p[0];
  #pragma unroll 4
  for (int g = 1; g < NST; ++g) m = fmaxf(m, p[(size_t)g * MQP]);
  out[i] = 1.0f - m;
}

extern "C" void kernel_launch(void* const* d_in, const int* in_sizes, int n_in,
                              void* d_out, int out_size, void* d_ws, size_t ws_size,
                              hipStream_t stream) {
  const float* q_feats = (const float*)d_in[0];  // (3, 8, 1370, 768) f32
  const float* s_feats = (const float*)d_in[1];  // (3, 32, 1370, 768) f32
  float* out = (float*)d_out;                    // (8, 1, 37, 37) f32

  char* ws = (char*)d_ws;
  const size_t xq_bytes = (size_t)NB * MQP * DDIM * 2;     // 18,874,368
  const size_t xs_bytes = (size_t)NSLAB * SCP * DDIM * 2;  // 69,206,016
  unsigned short* xq = (unsigned short*)ws;
  unsigned short* xs = (unsigned short*)(ws + xq_bytes);
  float* part        = (float*)(ws + xq_bytes + xs_bytes); // 8*44*1536 floats

  prep_kernel<<<dim3(MQP, NB), 192, 0, stream>>>(
      q_feats, xq, (size_t)NB * T_TOK * DDIM);
  prep_kernel<<<dim3(SCP, NSLAB), 192, 0, stream>>>(
      s_feats, xs, (size_t)NSLAB * T_TOK * DDIM);
  simmax_kernel<<<dim3(NMT, NST, NB), 256, 0, stream>>>(xq, xs, part);
  finalize_kernel<<<dim3((NB * SCV + 255) / 256), 256, 0, stream>>>(part, out);
}